// Round 1
// baseline (25.351 us; speedup 1.0000x reference)
//
#include <hip/hip_runtime.h>

// Problem constants (from reference)
#define VV     32000
#define DD     4096
#define BB     2
#define LL     2048
#define TIMG   32
#define TREG   264   // 33 * 8

// One block per output row (b,l). Each row: copy DD floats (16 KiB) from the
// selected source table. 256 threads x 4 float4 each = 1024 float4 = 4096 floats.
__global__ __launch_bounds__(256) void embed_gather_kernel(
    const float* __restrict__ weight,      // [VV, DD]
    const float* __restrict__ img_tok,     // [2, DD]
    const float* __restrict__ reg_tok,     // [2, DD]
    const float* __restrict__ img_emb,     // [BB, TIMG, DD]
    const float* __restrict__ reg_emb,     // [BB, TREG, DD]
    const int*   __restrict__ text,        // [BB, LL]
    float*       __restrict__ out)         // [BB, LL, DD]
{
    const int r = blockIdx.x;          // row index in [0, BB*LL)
    const int b = r >> 11;             // r / LL  (LL = 2048)
    const int t = text[r];             // wave-uniform broadcast

    const float* src;
    if (t < VV) {
        src = weight + (size_t)t * DD;
    } else if (t < VV + 2) {
        src = img_tok + (size_t)(t - VV) * DD;
    } else if (t < VV + 4) {
        src = reg_tok + (size_t)(t - VV - 2) * DD;
    } else if (t < VV + 4 + TIMG) {
        src = img_emb + ((size_t)b * TIMG + (t - VV - 4)) * DD;
    } else {
        src = reg_emb + ((size_t)b * TREG + (t - VV - 4 - TIMG)) * DD;
    }

    const float4* __restrict__ s4 = (const float4*)src;
    float4* __restrict__ d4 = (float4*)(out + (size_t)r * DD);

    const int tid = threadIdx.x;
#pragma unroll
    for (int i = 0; i < 4; ++i) {
        d4[tid + i * 256] = s4[tid + i * 256];
    }
}

extern "C" void kernel_launch(void* const* d_in, const int* in_sizes, int n_in,
                              void* d_out, int out_size, void* d_ws, size_t ws_size,
                              hipStream_t stream) {
    const float* weight  = (const float*)d_in[0];
    const float* img_tok = (const float*)d_in[1];
    const float* reg_tok = (const float*)d_in[2];
    const float* img_emb = (const float*)d_in[3];
    const float* reg_emb = (const float*)d_in[4];
    const int*   text    = (const int*)d_in[5];
    float* out = (float*)d_out;

    const int n_rows = BB * LL;  // 4096
    embed_gather_kernel<<<n_rows, 256, 0, stream>>>(
        weight, img_tok, reg_tok, img_emb, reg_emb, text, out);
}